// Round 5
// baseline (82.294 us; speedup 1.0000x reference)
//
#include <hip/hip_runtime.h>
#include <hip/hip_bf16.h>
#include <math.h>

#define BB 4
#define SS 1024
#define LL 128
#define PADL (LL + 4)          // col reads: bank (4i+j)%32, 2 lanes/bank = free
#define MAGIC 0x5CA1AB1Eu      // != 0xAAAAAAAA poison, != 0

// ws layout (32-bit words):
//   [0..255]    flags (uint)  - per-block completion flags (set to MAGIC)
//   [256..511]  part  (float) - per-block emit partials
//   [512..1023] elp   (float) - exp(logp0), 4 x 128
//   [1024..]    trans (float) - row-log-softmaxed transition, 128 x 128

__global__ __launch_bounds__(256) void crf_fused_kernel(
    const float* __restrict__ pred,
    const int* __restrict__ gt,
    const float* __restrict__ transition,
    unsigned int* __restrict__ ws_flags,
    float* __restrict__ ws_part,
    float* __restrict__ ws_elp,
    float* __restrict__ ws_trans,
    float* __restrict__ out)
{
    __shared__ float tr_s[LL][PADL];
    __shared__ int   gt_s[BB * SS];
    __shared__ float elp_s[BB][LL];
    __shared__ float pc[2][LL];
    __shared__ float pa[2][BB][LL];
    __shared__ float alpha_s[BB][LL];
    __shared__ float redA[4];
    __shared__ float emit_s[BB], gold_s[BB], fwd_s[BB];

    const int tid  = threadIdx.x;
    const int wave = tid >> 6;
    const int lane = tid & 63;
    const int blk  = blockIdx.x;
    const int row0 = blk * 16;

    // ================= Phase A: per-row LSE over 16 pred rows =================
    int gi[4];
    #pragma unroll
    for (int it = 0; it < 4; ++it) gi[it] = gt[row0 + it * 4 + wave];
    float2 v[4];
    #pragma unroll
    for (int it = 0; it < 4; ++it)
        v[it] = ((const float2*)(pred + (size_t)(row0 + it * 4 + wave) * LL))[lane];
    const bool do_trans = (blk < LL) && (wave == 0);
    float2 tv;
    if (do_trans) tv = ((const float2*)(transition + blk * LL))[lane];

    float local = 0.f;
    #pragma unroll
    for (int it = 0; it < 4; ++it) {
        float m = fmaxf(v[it].x, v[it].y);
        #pragma unroll
        for (int off = 32; off > 0; off >>= 1) m = fmaxf(m, __shfl_xor(m, off));
        float s = __expf(v[it].x - m) + __expf(v[it].y - m);
        #pragma unroll
        for (int off = 32; off > 0; off >>= 1) s += __shfl_xor(s, off);
        const float lse = m + __logf(s);

        // pred[r][g] is already in-wave: lane g>>1 holds it (component g&1)
        const int g = gi[it];                    // uniform across wave
        const float hold = (g & 1) ? v[it].y : v[it].x;
        local += __shfl(hold, g >> 1) - lse;

        // t==0 rows live in blocks {0,64,128,192}
        if (it == 0 && wave == 0 && (blk & 63) == 0) {
            const int b = blk >> 6;
            ws_elp[b * LL + 2 * lane]     = __expf(v[0].x - lse);
            ws_elp[b * LL + 2 * lane + 1] = __expf(v[0].y - lse);
        }
    }

    // transition row-log-softmax: block r (<128), wave 0
    if (do_trans) {
        float m = fmaxf(tv.x, tv.y);
        #pragma unroll
        for (int off = 32; off > 0; off >>= 1) m = fmaxf(m, __shfl_xor(m, off));
        float s = __expf(tv.x - m) + __expf(tv.y - m);
        #pragma unroll
        for (int off = 32; off > 0; off >>= 1) s += __shfl_xor(s, off);
        const float lse = m + __logf(s);
        float2 o; o.x = tv.x - lse; o.y = tv.y - lse;
        ((float2*)(ws_trans + blk * LL))[lane] = o;
    }

    if (lane == 0) redA[wave] = local;
    __syncthreads();
    if (tid == 0) {
        ws_part[blk] = redA[0] + redA[1] + redA[2] + redA[3];
        __threadfence();   // publish this block's ws stores (device scope)
        __hip_atomic_store(&ws_flags[blk], MAGIC, __ATOMIC_RELEASE,
                           __HIP_MEMORY_SCOPE_AGENT);
    }
    __syncthreads();

    // ---- check-once finisher election: the globally-last flag-setter sees all
    // 256 flags set; earlier blocks see a gap and exit. Multiple finishers are
    // possible and benign (phase B is idempotent, writes identical bytes).
    const bool ok = (__hip_atomic_load(&ws_flags[tid], __ATOMIC_ACQUIRE,
                                       __HIP_MEMORY_SCOPE_AGENT) == MAGIC);
    if (!__syncthreads_and((int)ok)) return;
    __threadfence();

    // ================= Phase B: finisher (256 threads) =======================
    #pragma unroll
    for (int k = 0; k < 4; ++k) {
        const int q = tid + k * 256;             // int4 index, 1024 total
        ((int4*)gt_s)[q] = ((const int4*)gt)[q];
    }
    #pragma unroll
    for (int k = 0; k < 16; ++k) {
        const int q = tid + k * 256;             // float4 index, 4096 total
        const int e = q * 4;
        *(float4*)&tr_s[e >> 7][e & (LL - 1)] = ((const float4*)ws_trans)[q];
    }
    #pragma unroll
    for (int k = 0; k < 2; ++k) {
        const int e = tid + k * 256;
        elp_s[e >> 7][e & (LL - 1)] = ws_elp[e];
    }
    {
        float p = ws_part[wave * 64 + lane];     // wave w reduces batch w
        #pragma unroll
        for (int off = 32; off > 0; off >>= 1) p += __shfl_xor(p, off);
        if (lane == 0) emit_s[wave] = p;
    }
    __syncthreads();

    // column exp-sum partials: thread (sub,j), sub owns 64 rows
    {
        const int sub = tid >> 7;
        const int j   = tid & (LL - 1);
        float sc = 0.f, s0 = 0.f, s1 = 0.f, s2 = 0.f, s3 = 0.f;
        #pragma unroll 8
        for (int k = 0; k < 64; ++k) {
            const int i = sub * 64 + k;
            const float e = __expf(tr_s[i][j]);
            sc += e;
            s0 += e * elp_s[0][i];
            s1 += e * elp_s[1][i];
            s2 += e * elp_s[2][i];
            s3 += e * elp_s[3][i];
        }
        pc[sub][j] = sc;
        pa[sub][0][j] = s0; pa[sub][1][j] = s1;
        pa[sub][2][j] = s2; pa[sub][3][j] = s3;
    }
    // gold path: wave b, lane strides 64, gathers from LDS
    {
        const int* gtb = gt_s + wave * SS;
        float g = 0.f;
        for (int t = lane; t < SS - 1; t += 64)
            g += tr_s[gtb[t]][gtb[t + 1]];
        #pragma unroll
        for (int off = 32; off > 0; off >>= 1) g += __shfl_xor(g, off);
        if (lane == 0) gold_s[wave] = g;
    }
    __syncthreads();

    // alpha[b,j]: thread (s,j) handles b = s and b = s+2
    {
        const int s = tid >> 7;
        const int j = tid & (LL - 1);
        const float csum = pc[0][j] + pc[1][j];
        const float lc   = (float)(SS - 2) * __logf(csum);
        #pragma unroll
        for (int b = 0; b < 2; ++b) {
            const int bb = s + 2 * b;
            const float asum = pa[0][bb][j] + pa[1][bb][j];
            alpha_s[bb][j] = __logf(asum) + lc;
        }
    }
    __syncthreads();

    // forward[b] = lse_j alpha[b,j]: wave b, 2 elements/lane
    {
        const float a0 = alpha_s[wave][lane];
        const float a1 = alpha_s[wave][lane + 64];
        float m = fmaxf(a0, a1);
        #pragma unroll
        for (int off = 32; off > 0; off >>= 1) m = fmaxf(m, __shfl_xor(m, off));
        float s = __expf(a0 - m) + __expf(a1 - m);
        #pragma unroll
        for (int off = 32; off > 0; off >>= 1) s += __shfl_xor(s, off);
        if (lane == 0) fwd_s[wave] = m + __logf(s);
    }
    __syncthreads();

    if (tid == 0) {
        float tot = 0.f;
        #pragma unroll
        for (int b = 0; b < BB; ++b)
            tot += emit_s[b] + gold_s[b] - fwd_s[b];
        out[0] = -tot * (1.0f / BB);
    }
}

extern "C" void kernel_launch(void* const* d_in, const int* in_sizes, int n_in,
                              void* d_out, int out_size, void* d_ws, size_t ws_size,
                              hipStream_t stream) {
    const float* pred       = (const float*)d_in[0];
    const int*   gt         = (const int*)d_in[1];
    const float* transition = (const float*)d_in[2];
    float* out = (float*)d_out;

    unsigned int* ws_flags = (unsigned int*)d_ws;
    float* ws_part  = (float*)d_ws + 256;
    float* ws_elp   = (float*)d_ws + 512;
    float* ws_trans = (float*)d_ws + 1024;   // 4 KiB offset, 16B-aligned

    crf_fused_kernel<<<256, 256, 0, stream>>>(
        pred, gt, transition, ws_flags, ws_part, ws_elp, ws_trans, out);
}

// Round 6
// 62.964 us; speedup vs baseline: 1.3070x; 1.3070x over previous
//
#include <hip/hip_runtime.h>
#include <hip/hip_bf16.h>
#include <math.h>

#define BB 4
#define SS 1024
#define LL 128

// ws layout (floats): [0..255] ws_part, [256..767] ws_elp (4 x 128, exp(logp0)),
// [768..768+16383] ws_trans (row-log-softmaxed transition). 768*4 B = 16B-aligned.

// Kernel 1: 256 blocks x 256 threads.
//  - every block: 16 pred rows -> row-LSE -> emit partial ws_part[block]
//  - blocks b*64 (b<4): wave 0 also writes ws_elp[b][:] = exp(pred[b,0,:]-lse)
//  - blocks r<128: wave 0 also row-log-softmaxes transition row r -> ws_trans
__global__ __launch_bounds__(256) void crf_rows_kernel(
    const float* __restrict__ pred,
    const int* __restrict__ gt,
    const float* __restrict__ transition,
    float* __restrict__ ws_part,
    float* __restrict__ ws_elp,
    float* __restrict__ ws_trans)
{
    const int wave = threadIdx.x >> 6;
    const int lane = threadIdx.x & 63;
    const int row0 = blockIdx.x * 16;

    // issue all global loads up front so latencies overlap
    int gi[4];
    #pragma unroll
    for (int it = 0; it < 4; ++it) gi[it] = gt[row0 + it * 4 + wave];
    float2 v[4];
    #pragma unroll
    for (int it = 0; it < 4; ++it)
        v[it] = ((const float2*)(pred + (size_t)(row0 + it * 4 + wave) * LL))[lane];
    const bool do_trans = (blockIdx.x < LL) && (wave == 0);
    float2 tv;
    if (do_trans) tv = ((const float2*)(transition + blockIdx.x * LL))[lane];

    float local = 0.f;
    #pragma unroll
    for (int it = 0; it < 4; ++it) {
        float m = fmaxf(v[it].x, v[it].y);
        #pragma unroll
        for (int off = 32; off > 0; off >>= 1) m = fmaxf(m, __shfl_xor(m, off));
        float s = __expf(v[it].x - m) + __expf(v[it].y - m);
        #pragma unroll
        for (int off = 32; off > 0; off >>= 1) s += __shfl_xor(s, off);
        const float lse = m + __logf(s);

        // pred[r][g] is already in-wave: lane g>>1 holds it (component g&1)
        const int g = gi[it];                    // uniform across wave
        const float hold = (g & 1) ? v[it].y : v[it].x;
        local += __shfl(hold, g >> 1) - lse;

        // t == 0 rows live in blocks {0,64,128,192}: stash exp(logp0)
        if (it == 0 && wave == 0 && (blockIdx.x & 63) == 0) {
            const int b = blockIdx.x >> 6;
            ws_elp[b * LL + 2 * lane]     = __expf(v[0].x - lse);
            ws_elp[b * LL + 2 * lane + 1] = __expf(v[0].y - lse);
        }
    }

    // transition row-log-softmax: block r (<128), wave 0
    if (do_trans) {
        float m = fmaxf(tv.x, tv.y);
        #pragma unroll
        for (int off = 32; off > 0; off >>= 1) m = fmaxf(m, __shfl_xor(m, off));
        float s = __expf(tv.x - m) + __expf(tv.y - m);
        #pragma unroll
        for (int off = 32; off > 0; off >>= 1) s += __shfl_xor(s, off);
        const float lse = m + __logf(s);
        float2 o; o.x = tv.x - lse; o.y = tv.y - lse;
        ((float2*)(ws_trans + blockIdx.x * LL))[lane] = o;
    }

    __shared__ float red[4];
    if (lane == 0) red[wave] = local;
    __syncthreads();
    if (threadIdx.x == 0)
        ws_part[blockIdx.x] = red[0] + red[1] + red[2] + red[3];
}

// Kernel 2: 1 block x 512 threads. Inputs pre-softmaxed; plain exp-sums
// (no max shift needed: tr_ls <= 0, elp <= 1), gold gathers, two short LSEs.
#define PADL (LL + 4)   // stride 132 floats: 16B-aligned rows, bank (4i+j)%32
__global__ __launch_bounds__(512) void crf_finish_kernel(
    const int* __restrict__ gt,
    const float* __restrict__ ws_part,
    const float* __restrict__ ws_elp,
    const float* __restrict__ ws_trans,
    float* __restrict__ out)
{
    __shared__ float tr_s[LL][PADL];
    __shared__ float elp_s[BB][LL];
    __shared__ float pc[4][LL];        // column exp-sum partials (c)
    __shared__ float pa[4][BB][LL];    // column exp-sum partials (alpha)
    __shared__ float emit_s[BB];
    __shared__ float wred[8];          // gold per-wave partials
    __shared__ float fm[8], fs[8];     // forward LSE per-wave partials

    const int tid  = threadIdx.x;
    const int lane = tid & 63;
    const int wave = tid >> 6;

    // ---- issue gold-path gt loads FIRST (latency hides behind staging) ----
    const int gb = tid >> 7;           // batch 0..3
    const int t0 = tid & (LL - 1);
    int gf[8], gs[8];
    {
        const int* gtb = gt + gb * SS;
        #pragma unroll
        for (int k = 0; k < 8; ++k) {
            const int t = t0 + k * LL;
            const bool val = (t < SS - 1);
            gf[k] = val ? gtb[t]     : 0;
            gs[k] = val ? gtb[t + 1] : 0;
        }
    }

    // ---- stage tr / elp / emit ----
    #pragma unroll
    for (int k = 0; k < 8; ++k) {               // 4096 float4s, 8 per thread
        const int e = (tid + k * 512) * 4;      // element index
        const int i = e >> 7, j = e & (LL - 1);
        *(float4*)&tr_s[i][j] = ((const float4*)ws_trans)[e >> 2];
    }
    elp_s[tid >> 7][tid & (LL - 1)] = ws_elp[tid];
    if (wave < BB) {                            // emit: wave w reduces batch w
        float p = ws_part[wave * 64 + lane];
        #pragma unroll
        for (int off = 32; off > 0; off >>= 1) p += __shfl_xor(p, off);
        if (lane == 0) emit_s[wave] = p;
    }
    __syncthreads();                                        // (A)

    // ---- column partials: thread (sub,j), sub owns 32 rows ----
    {
        const int sub = tid >> 7;
        const int j   = tid & (LL - 1);
        float sc = 0.f, s0 = 0.f, s1 = 0.f, s2 = 0.f, s3 = 0.f;
        #pragma unroll
        for (int k = 0; k < 32; ++k) {
            const int i = sub * 32 + k;
            const float e = __expf(tr_s[i][j]);
            sc += e;
            s0 += e * elp_s[0][i];
            s1 += e * elp_s[1][i];
            s2 += e * elp_s[2][i];
            s3 += e * elp_s[3][i];
        }
        pc[sub][j] = sc;
        pa[sub][0][j] = s0; pa[sub][1][j] = s1;
        pa[sub][2][j] = s2; pa[sub][3][j] = s3;
    }
    // ---- gold path partials from prefetched indices (tr_s read-only) ----
    {
        float g = 0.f;
        #pragma unroll
        for (int k = 0; k < 8; ++k) {
            const int t = t0 + k * LL;
            if (t < SS - 1) g += tr_s[gf[k]][gs[k]];
        }
        #pragma unroll
        for (int off = 32; off > 0; off >>= 1) g += __shfl_xor(g, off);
        if (lane == 0) wred[wave] = g;
    }
    __syncthreads();                                        // (B)

    // ---- alpha[b,j] + per-wave forward LSE partials ----
    {
        const int b = tid >> 7;
        const int j = tid & (LL - 1);
        const float csum = pc[0][j] + pc[1][j] + pc[2][j] + pc[3][j];
        const float asum = pa[0][b][j] + pa[1][b][j] + pa[2][b][j] + pa[3][b][j];
        const float alpha = __logf(asum) + (float)(SS - 2) * __logf(csum);

        float wm = alpha;
        #pragma unroll
        for (int off = 32; off > 0; off >>= 1) wm = fmaxf(wm, __shfl_xor(wm, off));
        float wsum = __expf(alpha - wm);
        #pragma unroll
        for (int off = 32; off > 0; off >>= 1) wsum += __shfl_xor(wsum, off);
        if (lane == 0) { fm[wave] = wm; fs[wave] = wsum; }
    }
    __syncthreads();                                        // (C)

    if (tid < BB) {
        const float m0 = fm[2 * tid], m1 = fm[2 * tid + 1];
        const float mm = fmaxf(m0, m1);
        const float fwd = mm + __logf(fs[2 * tid] * __expf(m0 - mm)
                                    + fs[2 * tid + 1] * __expf(m1 - mm));
        const float gold = wred[2 * tid] + wred[2 * tid + 1];
        fm[tid] = emit_s[tid] + gold - fwd;   // reuse fm as loss scratch
    }
    __syncthreads();                                        // (D)
    if (tid == 0)
        out[0] = -(fm[0] + fm[1] + fm[2] + fm[3]) * (1.0f / BB);
}

extern "C" void kernel_launch(void* const* d_in, const int* in_sizes, int n_in,
                              void* d_out, int out_size, void* d_ws, size_t ws_size,
                              hipStream_t stream) {
    const float* pred       = (const float*)d_in[0];
    const int*   gt         = (const int*)d_in[1];
    const float* transition = (const float*)d_in[2];
    float* out = (float*)d_out;

    float* ws_part  = (float*)d_ws;        // 256 floats
    float* ws_elp   = ws_part + 256;       // 512 floats
    float* ws_trans = ws_part + 768;       // 16384 floats, 16B-aligned offset

    crf_rows_kernel<<<(BB * SS) / 16, 256, 0, stream>>>(
        pred, gt, transition, ws_part, ws_elp, ws_trans);
    crf_finish_kernel<<<1, 512, 0, stream>>>(gt, ws_part, ws_elp, ws_trans, out);
}